// Round 21
// baseline (143.101 us; speedup 1.0000x reference)
//
#include <hip/hip_runtime.h>
#include <hip/hip_bf16.h>
#include <math.h>

#define B_ 2
#define S_ 2048
#define E_ 1024
#define H_ 16
#define D_ 64

typedef __attribute__((ext_vector_type(8))) short short8;
typedef __attribute__((ext_vector_type(4))) float f32x4;
typedef __attribute__((ext_vector_type(4))) unsigned short us4;
typedef __attribute__((ext_vector_type(8))) unsigned short us8;
typedef unsigned short ushort_t;

#define MFMA16 __builtin_amdgcn_mfma_f32_16x16x32_bf16

__device__ __forceinline__ ushort_t f2bf(float f) {
    unsigned int u = __float_as_uint(f);
    u += 0x7FFFu + ((u >> 16) & 1u);
    return (ushort_t)(u >> 16);
}
__device__ __forceinline__ float bf2f(ushort_t h) {
    return __uint_as_float((unsigned int)h << 16);
}
// native single-op conversion (round-8 proven: absmax identical)
__device__ __forceinline__ ushort_t f2bf_fast(float f) {
    __hip_bfloat16 h = __float2bfloat16(f);
    return *reinterpret_cast<ushort_t*>(&h);
}

// async global->LDS, 16B per lane; LDS dest = wave-uniform base + lane*16
__device__ __forceinline__ void gload16(const void* g, void* l) {
    __builtin_amdgcn_global_load_lds(
        (__attribute__((address_space(1))) void*)(unsigned long long)g,
        (__attribute__((address_space(3))) void*)(unsigned int)(unsigned long long)l,
        16, 0, 0);
}

// ---------------- merged prep: x->bf16 (blocks 0..2047) and W transpose+split
// (blocks 2048..3071). Both paths verbatim from the verified kernels. ----------------
__global__ __launch_bounds__(256)
void prep(const float* __restrict__ in, ushort_t* __restrict__ hi,
          const float* __restrict__ Wq, const float* __restrict__ Wk,
          const float* __restrict__ Wv, const float* __restrict__ Wo,
          ushort_t* __restrict__ Wth, ushort_t* __restrict__ Wtl)
{
    __shared__ float T[64][65];
    const int bid = blockIdx.x;
    const int tid = threadIdx.x;

    if (bid < 2048) {
        // ---- split_x path ----
        const size_t base = ((size_t)bid * 256 + tid) * 8;
        float v[8];
        *reinterpret_cast<float4*>(&v[0]) = *reinterpret_cast<const float4*>(&in[base]);
        *reinterpret_cast<float4*>(&v[4]) = *reinterpret_cast<const float4*>(&in[base + 4]);
        us8 h;
#pragma unroll
        for (int j = 0; j < 8; ++j) h[j] = f2bf(v[j]);
        *reinterpret_cast<us8*>(&hi[base]) = h;
        return;
    }

    // ---- wsplit_t path ----
    const int t  = bid - 2048;          // 0..1023
    const int z  = t >> 8;              // 0..3
    const int rem = t & 255;
    const int kt = ((rem >> 4) & 15) * 64;
    const int nt = (rem & 15) * 64;
    const float* W = (z == 0) ? Wq : (z == 1) ? Wk : (z == 2) ? Wv : Wo;

    const int lr = (tid >> 4) * 4;
    const int lc = (tid & 15) * 4;
#pragma unroll
    for (int i = 0; i < 4; ++i) {
        float4 v = *reinterpret_cast<const float4*>(&W[(size_t)(kt + lr + i) * 1024 + nt + lc]);
        T[lr + i][lc + 0] = v.x; T[lr + i][lc + 1] = v.y;
        T[lr + i][lc + 2] = v.z; T[lr + i][lc + 3] = v.w;
    }
    __syncthreads();

    const int n = tid >> 2;
    const int kc = (tid & 3) * 16;
    us8 h[2], l[2];
#pragma unroll
    for (int u = 0; u < 2; ++u)
#pragma unroll
        for (int j = 0; j < 8; ++j) {
            float v = T[kc + u * 8 + j][n];
            ushort_t hh = f2bf(v);
            h[u][j] = hh;
            l[u][j] = f2bf(v - bf2f(hh));
        }
    ushort_t* dh = Wth + ((size_t)z * 1024 + nt + n) * 1024 + kt + kc;
    ushort_t* dl = Wtl + ((size_t)z * 1024 + nt + n) * 1024 + kt + kc;
    *reinterpret_cast<us8*>(dh)     = h[0];
    *reinterpret_cast<us8*>(dh + 8) = h[1];
    *reinterpret_cast<us8*>(dl)     = l[0];
    *reinterpret_cast<us8*>(dl + 8) = l[1];
}

// ---------------- fused QKV GEMM, PLAIN bf16, 128x128, BK=32 ----------------
__global__ __launch_bounds__(256, 3)
void gemm_qkv(const ushort_t* __restrict__ xh, const ushort_t* __restrict__ Wth,
              const float* __restrict__ bq, const float* __restrict__ bk,
              const float* __restrict__ bv,
              ushort_t* __restrict__ Qb, ushort_t* __restrict__ Kb,
              ushort_t* __restrict__ Vb, float qalpha)
{
    __shared__ ushort_t As[128 * 32], Bs[128 * 32];
    const int which = blockIdx.x >> 3;
    const int n0 = (blockIdx.x & 7) * 128;
    const int m0 = blockIdx.y * 128;
    const ushort_t* Bh = Wth + (size_t)which * 1024 * 1024;
    const float* bias = (which == 0) ? bq : (which == 1) ? bk : bv;
    ushort_t* out = (which == 0) ? Qb : (which == 1) ? Kb : Vb;
    const float alpha = (which == 0) ? qalpha : 1.0f;

    const int tid  = threadIdx.x;
    const int lane = tid & 63;
    const int w    = tid >> 6;
    const int l15  = lane & 15;
    const int g    = lane >> 4;
    const int wr   = w >> 1;
    const int wc   = w & 1;

    const int sr  = lane >> 2;
    const int scz = (lane & 3) ^ ((sr >> 1) & 3);
    const int sc  = scz * 8;
    const int j0 = w * 2, j1 = j0 + 1;

    const ushort_t* gA0 = xh + (size_t)(m0 + j0 * 16 + sr) * 1024 + sc;
    const ushort_t* gA1 = xh + (size_t)(m0 + j1 * 16 + sr) * 1024 + sc;
    const ushort_t* gB0 = Bh + (size_t)(n0 + j0 * 16 + sr) * 1024 + sc;
    const ushort_t* gB1 = Bh + (size_t)(n0 + j1 * 16 + sr) * 1024 + sc;

    const int sx  = (l15 >> 1) & 3;
    const int rd1 = (((g >> 1) + 0) ^ sx) * 8 + (g & 1) * 4;
    const int rd2 = (((g >> 1) + 2) ^ sx) * 8 + (g & 1) * 4;

    f32x4 acc[4][4];
#pragma unroll
    for (int i = 0; i < 4; ++i)
#pragma unroll
        for (int j = 0; j < 4; ++j) { acc[i][j][0] = 0.f; acc[i][j][1] = 0.f; acc[i][j][2] = 0.f; acc[i][j][3] = 0.f; }

    for (int kt = 0; kt < 32; ++kt) {
        const int k0 = kt * 32;
        if (kt) __syncthreads();
        gload16(gA0 + k0, As + j0 * 512);
        gload16(gA1 + k0, As + j1 * 512);
        gload16(gB0 + k0, Bs + j0 * 512);
        gload16(gB1 + k0, Bs + j1 * 512);
        asm volatile("s_waitcnt vmcnt(0)" ::: "memory");
        __syncthreads();

        short8 bh[4];
#pragma unroll
        for (int nb = 0; nb < 4; ++nb) {
            const int rb = (wc * 64 + nb * 16 + l15) * 32;
            union { us4 h[2]; short8 s; } u;
            u.h[0] = *reinterpret_cast<const us4*>(Bs + rb + rd1);
            u.h[1] = *reinterpret_cast<const us4*>(Bs + rb + rd2);
            bh[nb] = u.s;
        }
#pragma unroll
        for (int mb = 0; mb < 4; ++mb) {
            const int rb = (wr * 64 + mb * 16 + l15) * 32;
            union { us4 h[2]; short8 s; } ua;
            ua.h[0] = *reinterpret_cast<const us4*>(As + rb + rd1);
            ua.h[1] = *reinterpret_cast<const us4*>(As + rb + rd2);
            const short8 ah = ua.s;
#pragma unroll
            for (int nb = 0; nb < 4; ++nb)
                acc[mb][nb] = MFMA16(ah, bh[nb], acc[mb][nb], 0, 0, 0);
        }
    }

    float bvv[4];
#pragma unroll
    for (int nb = 0; nb < 4; ++nb) bvv[nb] = bias[n0 + wc * 64 + nb * 16 + l15];
#pragma unroll
    for (int mb = 0; mb < 4; ++mb)
#pragma unroll
        for (int r = 0; r < 4; ++r) {
            const size_t row = m0 + wr * 64 + mb * 16 + 4 * g + r;
#pragma unroll
            for (int nb = 0; nb < 4; ++nb) {
                const float vv = (acc[mb][nb][r] + bvv[nb]) * alpha;
                out[row * 1024 + n0 + wc * 64 + nb * 16 + l15] = f2bf(vv);
            }
        }
}

// ---------------- output GEMM bf16x3, 128x64 tiles (512 blocks, 2/CU) ----------------
__global__ __launch_bounds__(256, 2)
void gemm_o64(const ushort_t* __restrict__ Ah, const ushort_t* __restrict__ Al,
              const ushort_t* __restrict__ Bh, const ushort_t* __restrict__ Bl,
              const float* __restrict__ bias, float* __restrict__ out)
{
    __shared__ ushort_t AsH[128 * 32], AsL[128 * 32], BsH[64 * 32], BsL[64 * 32];
    const int tid  = threadIdx.x;
    const int lane = tid & 63;
    const int w    = tid >> 6;
    const int l15  = lane & 15;
    const int g    = lane >> 4;
    const int wr   = w >> 1;          // 0..1 -> 64 rows
    const int wc   = w & 1;           // 0..1 -> 32 cols
    const int n0 = blockIdx.x * 64;
    const int m0 = blockIdx.y * 128;

    const int sr  = lane >> 2;
    const int scz = (lane & 3) ^ ((sr >> 1) & 3);
    const int sc  = scz * 8;
    const int ja0 = 2 * w, ja1 = 2 * w + 1;

    const ushort_t* gAh0 = Ah + (size_t)(m0 + ja0 * 16 + sr) * 1024 + sc;
    const ushort_t* gAh1 = Ah + (size_t)(m0 + ja1 * 16 + sr) * 1024 + sc;
    const ushort_t* gAl0 = Al + (size_t)(m0 + ja0 * 16 + sr) * 1024 + sc;
    const ushort_t* gAl1 = Al + (size_t)(m0 + ja1 * 16 + sr) * 1024 + sc;
    const ushort_t* gBh0 = Bh + (size_t)(n0 + w * 16 + sr) * 1024 + sc;
    const ushort_t* gBl0 = Bl + (size_t)(n0 + w * 16 + sr) * 1024 + sc;

    const int sx  = (l15 >> 1) & 3;
    const int rd1 = (((g >> 1) + 0) ^ sx) * 8 + (g & 1) * 4;
    const int rd2 = (((g >> 1) + 2) ^ sx) * 8 + (g & 1) * 4;

    f32x4 acc[4][2];
#pragma unroll
    for (int i = 0; i < 4; ++i)
#pragma unroll
        for (int j = 0; j < 2; ++j) { acc[i][j][0] = 0.f; acc[i][j][1] = 0.f; acc[i][j][2] = 0.f; acc[i][j][3] = 0.f; }

    for (int kt = 0; kt < 32; ++kt) {
        const int k0 = kt * 32;
        if (kt) __syncthreads();
        gload16(gAh0 + k0, AsH + ja0 * 512);
        gload16(gAh1 + k0, AsH + ja1 * 512);
        gload16(gAl0 + k0, AsL + ja0 * 512);
        gload16(gAl1 + k0, AsL + ja1 * 512);
        gload16(gBh0 + k0, BsH + w * 512);
        gload16(gBl0 + k0, BsL + w * 512);
        asm volatile("s_waitcnt vmcnt(0)" ::: "memory");
        __syncthreads();

        short8 bh[2], bl[2];
#pragma unroll
        for (int nb = 0; nb < 2; ++nb) {
            const int rb = (wc * 32 + nb * 16 + l15) * 32;
            union { us4 h[2]; short8 s; } u;
            u.h[0] = *reinterpret_cast<const us4*>(BsH + rb + rd1);
            u.h[1] = *reinterpret_cast<const us4*>(BsH + rb + rd2);
            bh[nb] = u.s;
            union { us4 h[2]; short8 s; } v;
            v.h[0] = *reinterpret_cast<const us4*>(BsL + rb + rd1);
            v.h[1] = *reinterpret_cast<const us4*>(BsL + rb + rd2);
            bl[nb] = v.s;
        }
#pragma unroll
        for (int mb = 0; mb < 4; ++mb) {
            const int rb = (wr * 64 + mb * 16 + l15) * 32;
            union { us4 h[2]; short8 s; } ua;
            ua.h[0] = *reinterpret_cast<const us4*>(AsH + rb + rd1);
            ua.h[1] = *reinterpret_cast<const us4*>(AsH + rb + rd2);
            union { us4 h[2]; short8 s; } ul;
            ul.h[0] = *reinterpret_cast<const us4*>(AsL + rb + rd1);
            ul.h[1] = *reinterpret_cast<const us4*>(AsL + rb + rd2);
            const short8 ah = ua.s, al = ul.s;
#pragma unroll
            for (int nb = 0; nb < 2; ++nb) {
                acc[mb][nb] = MFMA16(ah, bh[nb], acc[mb][nb], 0, 0, 0);
                acc[mb][nb] = MFMA16(al, bh[nb], acc[mb][nb], 0, 0, 0);
                acc[mb][nb] = MFMA16(ah, bl[nb], acc[mb][nb], 0, 0, 0);
            }
        }
    }

    float bvv[2];
#pragma unroll
    for (int nb = 0; nb < 2; ++nb) bvv[nb] = bias[n0 + wc * 32 + nb * 16 + l15];
#pragma unroll
    for (int mb = 0; mb < 4; ++mb)
#pragma unroll
        for (int r = 0; r < 4; ++r) {
            const size_t row = m0 + wr * 64 + mb * 16 + 4 * g + r;
#pragma unroll
            for (int nb = 0; nb < 2; ++nb)
                out[row * 1024 + n0 + wc * 32 + nb * 16 + l15] = acc[mb][nb][r] + bvv[nb];
        }
}

// ---------------- MFMA bf16 flash attention, KVBLK=256, 8 waves / 256 q-rows ----------------
// Round-20 verified structure (lacc row-sum on MFMA pipe). New this round:
// (1) tree-structured row-max (exact; breaks the 64-deep serial fmax chain),
// (2) defer-max THR=8 (T13): skip rescale while tile max stays within 8 of
//     the running max — P bounded by 2^8, exact online-softmax algebra kept.
__global__ __launch_bounds__(512, 2)
void attn_mfma(const ushort_t* __restrict__ Q, const ushort_t* __restrict__ K,
               const ushort_t* __restrict__ V, ushort_t* __restrict__ XHh,
               ushort_t* __restrict__ XHl)
{
    __shared__ __align__(16) ushort_t Kf[4][4096];   // [hf] 32 KB
    __shared__ __align__(16) ushort_t Vf[4][4096];   // 32 KB

    const int tid  = threadIdx.x;
    const int w    = tid >> 6;        // 0..7
    const int lane = tid & 63;
    const int l15  = lane & 15;
    const int g    = lane >> 4;

    // 1D grid 256: 8 same-head q-blocks share L%8 -> same XCD L2 (bijective)
    const int L  = blockIdx.x;
    const int qb = (L >> 3) & 7;
    const int bh = (L & 7) | ((L >> 6) << 3);
    const int b  = bh >> 4;
    const int hh = bh & 15;
    const size_t hoff = (size_t)b * S_ * E_ + (size_t)hh * S_ * D_;
    const ushort_t* Qh = Q + hoff;
    const ushort_t* Kh = K + hoff;
    const ushort_t* Vh = V + hoff;

    const int qw = qb * 256 + w * 32;   // this wave's 32 q-rows

    short8 qf[2][2];
#pragma unroll
    for (int qg = 0; qg < 2; ++qg)
#pragma unroll
        for (int m = 0; m < 2; ++m) {
            const ushort_t* src = &Qh[(size_t)(qw + 16 * qg + l15) * D_ + 32 * m + 4 * g];
            us4 lo = *reinterpret_cast<const us4*>(src);
            us4 hi = *reinterpret_cast<const us4*>(src + 16);
            union { us4 h[2]; short8 s; } u;
            u.h[0] = lo; u.h[1] = hi;
            qf[qg][m] = u.s;
        }

    // all-ones bf16 B-fragment for the l row-sum MFMA
    short8 onesf;
#pragma unroll
    for (int j = 0; j < 8; ++j) onesf[j] = (short)0x3F80;

    // staging: group (tid>>8) stages halves {2g, 2g+1}; verbatim 256-thread mapping
    const int hfS0 = (tid >> 8) * 2;
    const int ltid = tid & 255;
    const int kr  = ltid >> 2;
    const int kc0 = ltid & 3;
    const int kkc = ltid >> 4;
    const int vdc = ltid & 15;
    const int vmc = kkc >> 3;
    const int vh  = (kkc >> 2) & 1;
    const int vg  = kkc & 3;
    const int vn  = vdc >> 2;

    f32x4 o[2][4];
    f32x4 lacc[2];
#pragma unroll
    for (int qg = 0; qg < 2; ++qg) {
#pragma unroll
        for (int n = 0; n < 4; ++n)
#pragma unroll
            for (int r = 0; r < 4; ++r) o[qg][n][r] = 0.f;
#pragma unroll
        for (int r = 0; r < 4; ++r) lacc[qg][r] = 0.f;
    }

    float mrun[2] = {-1e30f, -1e30f};

    for (int kt = 0; kt < S_ / 256; ++kt) {
        // ---- global loads for this group's two halves (before barrier) ----
        us8 kreg[2][2];
        us4 vreg[2][4];
#pragma unroll
        for (int lh = 0; lh < 2; ++lh) {
            const int rowb = kt * 256 + (hfS0 + lh) * 64;
#pragma unroll
            for (int u = 0; u < 2; ++u)
                kreg[lh][u] = *reinterpret_cast<const us8*>(&Kh[(size_t)(rowb + kr) * D_ + 8 * (kc0 + 4 * u)]);
#pragma unroll
            for (int i = 0; i < 4; ++i)
                vreg[lh][i] = *reinterpret_cast<const us4*>(&Vh[(size_t)(rowb + 4 * kkc + i) * D_ + 4 * vdc]);
        }

        __syncthreads();   // previous tile's readers done

        // ---- LDS writes (verbatim verified mapping, own two halves) ----
#pragma unroll
        for (int lh = 0; lh < 2; ++lh) {
            const int hf = hfS0 + lh;
#pragma unroll
            for (int u = 0; u < 2; ++u) {
                const int c8 = kc0 + 4 * u;
                const int m = c8 >> 2;
                const int h = (c8 >> 1) & 1;
#pragma unroll
                for (int jh = 0; jh < 2; ++jh) {
                    const int gk = (2 * c8 + jh) & 3;
                    const int slot = gk * 16 + (kr & 15);
                    us4 val;
#pragma unroll
                    for (int i = 0; i < 4; ++i) val[i] = (ushort_t)kreg[lh][u][4 * jh + i];
                    *reinterpret_cast<us4*>(&Kf[hf][((((kr >> 4) * 2 + m) * 64 + slot) * 8) + h * 4]) = val;
                }
            }
#pragma unroll
            for (int jj = 0; jj < 4; ++jj) {
                us4 val;
#pragma unroll
                for (int i = 0; i < 4; ++i) val[i] = vreg[lh][i][jj];
                const int pos  = 4 * (vdc & 3) + jj;
                const int posx = pos ^ vg ^ (vn << 2);
                const int slot = vg * 16 + posx;
                *reinterpret_cast<us4*>(&Vf[hf][(((vn * 2 + vmc) * 64 + slot) * 8) + vh * 4]) = val;
            }
        }
        __syncthreads();

        // ---- QK^T for all four halves: s[qg][hf*4+kkb] ----
        f32x4 s[2][16];
#pragma unroll
        for (int hf = 0; hf < 4; ++hf) {
            short8 kf[4][2];
#pragma unroll
            for (int kkb = 0; kkb < 4; ++kkb)
#pragma unroll
                for (int m = 0; m < 2; ++m)
                    kf[kkb][m] = *reinterpret_cast<const short8*>(&Kf[hf][((kkb * 2 + m) * 64 + lane) * 8]);
#pragma unroll
            for (int qg = 0; qg < 2; ++qg)
#pragma unroll
                for (int kkb = 0; kkb < 4; ++kkb) {
                    f32x4 z; z[0] = 0.f; z[1] = 0.f; z[2] = 0.f; z[3] = 0.f;
                    z = MFMA16(kf[kkb][0], qf[qg][0], z, 0, 0, 0);
                    s[qg][hf * 4 + kkb] = MFMA16(kf[kkb][1], qf[qg][1], z, 0, 0, 0);
                }
        }

        // ---- online-softmax update per 256 KV rows (tree max + defer-max) ----
#pragma unroll
        for (int qg = 0; qg < 2; ++qg) {
            // exact pairwise-tree row max (depth ~6 vs serial 64)
            float tm[8];
#pragma unroll
            for (int j = 0; j < 8; ++j) {
                const float a0 = fmaxf(fmaxf(s[qg][2 * j][0], s[qg][2 * j][1]),
                                       fmaxf(s[qg][2 * j][2], s[qg][2 * j][3]));
                const float a1 = fmaxf(fmaxf(s[qg][2 * j + 1][0], s[qg][2 * j + 1][1]),
                                       fmaxf(s[qg][2 * j + 1][2], s[qg][2 * j + 1][3]));
                tm[j] = fmaxf(a0, a1);
            }
            float t = fmaxf(fmaxf(fmaxf(tm[0], tm[1]), fmaxf(tm[2], tm[3])),
                            fmaxf(fmaxf(tm[4], tm[5]), fmaxf(tm[6], tm[7])));
            t = fmaxf(t, __shfl_xor(t, 16));
            t = fmaxf(t, __shfl_xor(t, 32));

            // defer-max (T13): skip rescale while tile max within THR=8 of mrun
            if (!__all(t <= mrun[qg] + 8.0f)) {
                const float mnew = fmaxf(mrun[qg], t);
                const float corr = __builtin_amdgcn_exp2f(mrun[qg] - mnew);
                mrun[qg] = mnew;
#pragma unroll
                for (int r = 0; r < 4; ++r) {
                    const float c4 = __shfl(corr, 4 * g + r);
                    lacc[qg][r] *= c4;
#pragma unroll
                    for (int n = 0; n < 4; ++n) o[qg][n][r] *= c4;
                }
            }

#pragma unroll
            for (int j = 0; j < 16; ++j)
#pragma unroll
                for (int r = 0; r < 4; ++r)
                    s[qg][j][r] = __builtin_amdgcn_exp2f(s[qg][j][r] - mrun[qg]);
        }

        // ---- PV per half (pa from s[qg][hf*4+..], vf from Vf[hf]); l via MFMA ----
#pragma unroll
        for (int hf = 0; hf < 4; ++hf) {
            short8 vf[4][2];
#pragma unroll
            for (int n = 0; n < 4; ++n)
#pragma unroll
                for (int m = 0; m < 2; ++m) {
                    const int posr = (lane & 15) ^ (lane >> 4) ^ (n << 2);
                    const int slot = (lane & 48) | posr;
                    vf[n][m] = *reinterpret_cast<const short8*>(&Vf[hf][((n * 2 + m) * 64 + slot) * 8]);
                }
#pragma unroll
            for (int qg = 0; qg < 2; ++qg) {
                short8 pa[2];
#pragma unroll
                for (int m = 0; m < 2; ++m) {
                    us8 tmp;
#pragma unroll
                    for (int r = 0; r < 4; ++r) {
                        tmp[r]     = f2bf_fast(s[qg][hf * 4 + 2 * m][r]);
                        tmp[r + 4] = f2bf_fast(s[qg][hf * 4 + 2 * m + 1][r]);
                    }
                    union { us8 u8; short8 s8; } cvt; cvt.u8 = tmp;
                    pa[m] = cvt.s8;
                }
#pragma unroll
                for (int n = 0; n < 4; ++n) {
                    o[qg][n] = MFMA16(pa[0], vf[n][0], o[qg][n], 0, 0, 0);
                    o[qg][n] = MFMA16(pa[1], vf[n][1], o[qg][n], 0, 0, 0);
                }
                lacc[qg] = MFMA16(pa[0], onesf, lacc[qg], 0, 0, 0);
                lacc[qg] = MFMA16(pa[1], onesf, lacc[qg], 0, 0, 0);
            }
        }
    }

#pragma unroll
    for (int qg = 0; qg < 2; ++qg) {
#pragma unroll
        for (int r = 0; r < 4; ++r) {
            const float iv = 1.f / lacc[qg][r];   // same C-layout as o: no shfl
            const int row = qw + 16 * qg + 4 * g + r;
            const size_t base = ((size_t)b * S_ + row) * E_ + hh * D_ + l15;
#pragma unroll
            for (int n = 0; n < 4; ++n) {
                const float vv = o[qg][n][r] * iv;
                const ushort_t hi = f2bf(vv);
                XHh[base + 16 * n] = hi;
                XHl[base + 16 * n] = f2bf(vv - bf2f(hi));
            }
        }
    }
}

extern "C" void kernel_launch(void* const* d_in, const int* in_sizes, int n_in,
                              void* d_out, int out_size, void* d_ws, size_t ws_size,
                              hipStream_t stream) {
    (void)in_sizes; (void)n_in; (void)out_size; (void)ws_size;
    const float* x  = (const float*)d_in[0];
    const float* Wq = (const float*)d_in[1];
    const float* bq = (const float*)d_in[2];
    const float* Wk = (const float*)d_in[3];
    const float* bk = (const float*)d_in[4];
    const float* Wv = (const float*)d_in[5];
    const float* bv = (const float*)d_in[6];
    const float* Wo = (const float*)d_in[7];
    const float* bo = (const float*)d_in[8];
    float* out = (float*)d_out;

    char* ws = (char*)d_ws;
    const size_t MB8 = 8ull * 1024 * 1024;
    ushort_t* xhi = (ushort_t*)(ws);             // 8 MB, reused as XHh after QKV
    ushort_t* XHl = (ushort_t*)(ws + MB8);       // 8 MB
    ushort_t* Wth = (ushort_t*)(ws + 2 * MB8);   // 8 MB  [4][1024][1024]
    ushort_t* Wtl = (ushort_t*)(ws + 3 * MB8);   // 8 MB
    ushort_t* Qb  = (ushort_t*)(ws + 4 * MB8);   // 8 MB
    ushort_t* Kb  = (ushort_t*)(ws + 5 * MB8);   // 8 MB
    ushort_t* Vb  = (ushort_t*)(ws + 6 * MB8);   // 8 MB  (total 56 MB)
    ushort_t* XHh = xhi;

    const float qalpha = 0.125f * 1.4426950408889634f;  // 1/sqrt(D) * log2(e)

    prep<<<dim3(3072), dim3(256), 0, stream>>>(x, xhi, Wq, Wk, Wv, Wo, Wth, Wtl);

    gemm_qkv<<<dim3(24, 32), dim3(256), 0, stream>>>(xhi, Wth,
                                                     bq, bk, bv, Qb, Kb, Vb, qalpha);

    attn_mfma<<<dim3(256), dim3(512), 0, stream>>>(Qb, Kb, Vb, XHh, XHl);

    gemm_o64<<<dim3(16, 32), dim3(256), 0, stream>>>(XHh, XHl,
                                                     Wth + 3ull * 1024 * 1024,
                                                     Wtl + 3ull * 1024 * 1024,
                                                     bo, out);
}

// Round 22
// 142.220 us; speedup vs baseline: 1.0062x; 1.0062x over previous
//
#include <hip/hip_runtime.h>
#include <hip/hip_bf16.h>
#include <math.h>

#define B_ 2
#define S_ 2048
#define E_ 1024
#define H_ 16
#define D_ 64

typedef __attribute__((ext_vector_type(8))) short short8;
typedef __attribute__((ext_vector_type(4))) float f32x4;
typedef __attribute__((ext_vector_type(4))) unsigned short us4;
typedef __attribute__((ext_vector_type(8))) unsigned short us8;
typedef unsigned short ushort_t;

#define MFMA16 __builtin_amdgcn_mfma_f32_16x16x32_bf16

__device__ __forceinline__ ushort_t f2bf(float f) {
    unsigned int u = __float_as_uint(f);
    u += 0x7FFFu + ((u >> 16) & 1u);
    return (ushort_t)(u >> 16);
}
__device__ __forceinline__ float bf2f(ushort_t h) {
    return __uint_as_float((unsigned int)h << 16);
}
// native single-op conversion (round-8 proven: absmax identical)
__device__ __forceinline__ ushort_t f2bf_fast(float f) {
    __hip_bfloat16 h = __float2bfloat16(f);
    return *reinterpret_cast<ushort_t*>(&h);
}

// async global->LDS, 16B per lane; LDS dest = wave-uniform base + lane*16
__device__ __forceinline__ void gload16(const void* g, void* l) {
    __builtin_amdgcn_global_load_lds(
        (__attribute__((address_space(1))) void*)(unsigned long long)g,
        (__attribute__((address_space(3))) void*)(unsigned int)(unsigned long long)l,
        16, 0, 0);
}

// ---------------- merged prep: x->bf16 (blocks 0..2047) and W transpose+split
// (blocks 2048..3071). Both paths verbatim from the verified kernels. ----------------
__global__ __launch_bounds__(256)
void prep(const float* __restrict__ in, ushort_t* __restrict__ hi,
          const float* __restrict__ Wq, const float* __restrict__ Wk,
          const float* __restrict__ Wv, const float* __restrict__ Wo,
          ushort_t* __restrict__ Wth, ushort_t* __restrict__ Wtl)
{
    __shared__ float T[64][65];
    const int bid = blockIdx.x;
    const int tid = threadIdx.x;

    if (bid < 2048) {
        // ---- split_x path ----
        const size_t base = ((size_t)bid * 256 + tid) * 8;
        float v[8];
        *reinterpret_cast<float4*>(&v[0]) = *reinterpret_cast<const float4*>(&in[base]);
        *reinterpret_cast<float4*>(&v[4]) = *reinterpret_cast<const float4*>(&in[base + 4]);
        us8 h;
#pragma unroll
        for (int j = 0; j < 8; ++j) h[j] = f2bf(v[j]);
        *reinterpret_cast<us8*>(&hi[base]) = h;
        return;
    }

    // ---- wsplit_t path ----
    const int t  = bid - 2048;          // 0..1023
    const int z  = t >> 8;              // 0..3
    const int rem = t & 255;
    const int kt = ((rem >> 4) & 15) * 64;
    const int nt = (rem & 15) * 64;
    const float* W = (z == 0) ? Wq : (z == 1) ? Wk : (z == 2) ? Wv : Wo;

    const int lr = (tid >> 4) * 4;
    const int lc = (tid & 15) * 4;
#pragma unroll
    for (int i = 0; i < 4; ++i) {
        float4 v = *reinterpret_cast<const float4*>(&W[(size_t)(kt + lr + i) * 1024 + nt + lc]);
        T[lr + i][lc + 0] = v.x; T[lr + i][lc + 1] = v.y;
        T[lr + i][lc + 2] = v.z; T[lr + i][lc + 3] = v.w;
    }
    __syncthreads();

    const int n = tid >> 2;
    const int kc = (tid & 3) * 16;
    us8 h[2], l[2];
#pragma unroll
    for (int u = 0; u < 2; ++u)
#pragma unroll
        for (int j = 0; j < 8; ++j) {
            float v = T[kc + u * 8 + j][n];
            ushort_t hh = f2bf(v);
            h[u][j] = hh;
            l[u][j] = f2bf(v - bf2f(hh));
        }
    ushort_t* dh = Wth + ((size_t)z * 1024 + nt + n) * 1024 + kt + kc;
    ushort_t* dl = Wtl + ((size_t)z * 1024 + nt + n) * 1024 + kt + kc;
    *reinterpret_cast<us8*>(dh)     = h[0];
    *reinterpret_cast<us8*>(dh + 8) = h[1];
    *reinterpret_cast<us8*>(dl)     = l[0];
    *reinterpret_cast<us8*>(dl + 8) = l[1];
}

// ---------------- fused QKV GEMM, PLAIN bf16, 128x128, BK=32 ----------------
__global__ __launch_bounds__(256, 3)
void gemm_qkv(const ushort_t* __restrict__ xh, const ushort_t* __restrict__ Wth,
              const float* __restrict__ bq, const float* __restrict__ bk,
              const float* __restrict__ bv,
              ushort_t* __restrict__ Qb, ushort_t* __restrict__ Kb,
              ushort_t* __restrict__ Vb, float qalpha)
{
    __shared__ ushort_t As[128 * 32], Bs[128 * 32];
    const int which = blockIdx.x >> 3;
    const int n0 = (blockIdx.x & 7) * 128;
    const int m0 = blockIdx.y * 128;
    const ushort_t* Bh = Wth + (size_t)which * 1024 * 1024;
    const float* bias = (which == 0) ? bq : (which == 1) ? bk : bv;
    ushort_t* out = (which == 0) ? Qb : (which == 1) ? Kb : Vb;
    const float alpha = (which == 0) ? qalpha : 1.0f;

    const int tid  = threadIdx.x;
    const int lane = tid & 63;
    const int w    = tid >> 6;
    const int l15  = lane & 15;
    const int g    = lane >> 4;
    const int wr   = w >> 1;
    const int wc   = w & 1;

    const int sr  = lane >> 2;
    const int scz = (lane & 3) ^ ((sr >> 1) & 3);
    const int sc  = scz * 8;
    const int j0 = w * 2, j1 = j0 + 1;

    const ushort_t* gA0 = xh + (size_t)(m0 + j0 * 16 + sr) * 1024 + sc;
    const ushort_t* gA1 = xh + (size_t)(m0 + j1 * 16 + sr) * 1024 + sc;
    const ushort_t* gB0 = Bh + (size_t)(n0 + j0 * 16 + sr) * 1024 + sc;
    const ushort_t* gB1 = Bh + (size_t)(n0 + j1 * 16 + sr) * 1024 + sc;

    const int sx  = (l15 >> 1) & 3;
    const int rd1 = (((g >> 1) + 0) ^ sx) * 8 + (g & 1) * 4;
    const int rd2 = (((g >> 1) + 2) ^ sx) * 8 + (g & 1) * 4;

    f32x4 acc[4][4];
#pragma unroll
    for (int i = 0; i < 4; ++i)
#pragma unroll
        for (int j = 0; j < 4; ++j) { acc[i][j][0] = 0.f; acc[i][j][1] = 0.f; acc[i][j][2] = 0.f; acc[i][j][3] = 0.f; }

    for (int kt = 0; kt < 32; ++kt) {
        const int k0 = kt * 32;
        if (kt) __syncthreads();
        gload16(gA0 + k0, As + j0 * 512);
        gload16(gA1 + k0, As + j1 * 512);
        gload16(gB0 + k0, Bs + j0 * 512);
        gload16(gB1 + k0, Bs + j1 * 512);
        asm volatile("s_waitcnt vmcnt(0)" ::: "memory");
        __syncthreads();

        short8 bh[4];
#pragma unroll
        for (int nb = 0; nb < 4; ++nb) {
            const int rb = (wc * 64 + nb * 16 + l15) * 32;
            union { us4 h[2]; short8 s; } u;
            u.h[0] = *reinterpret_cast<const us4*>(Bs + rb + rd1);
            u.h[1] = *reinterpret_cast<const us4*>(Bs + rb + rd2);
            bh[nb] = u.s;
        }
#pragma unroll
        for (int mb = 0; mb < 4; ++mb) {
            const int rb = (wr * 64 + mb * 16 + l15) * 32;
            union { us4 h[2]; short8 s; } ua;
            ua.h[0] = *reinterpret_cast<const us4*>(As + rb + rd1);
            ua.h[1] = *reinterpret_cast<const us4*>(As + rb + rd2);
            const short8 ah = ua.s;
#pragma unroll
            for (int nb = 0; nb < 4; ++nb)
                acc[mb][nb] = MFMA16(ah, bh[nb], acc[mb][nb], 0, 0, 0);
        }
    }

    float bvv[4];
#pragma unroll
    for (int nb = 0; nb < 4; ++nb) bvv[nb] = bias[n0 + wc * 64 + nb * 16 + l15];
#pragma unroll
    for (int mb = 0; mb < 4; ++mb)
#pragma unroll
        for (int r = 0; r < 4; ++r) {
            const size_t row = m0 + wr * 64 + mb * 16 + 4 * g + r;
#pragma unroll
            for (int nb = 0; nb < 4; ++nb) {
                const float vv = (acc[mb][nb][r] + bvv[nb]) * alpha;
                out[row * 1024 + n0 + wc * 64 + nb * 16 + l15] = f2bf(vv);
            }
        }
}

// ---------------- output GEMM bf16x3, 128x64 tiles (512 blocks, 2/CU) ----------------
__global__ __launch_bounds__(256, 2)
void gemm_o64(const ushort_t* __restrict__ Ah, const ushort_t* __restrict__ Al,
              const ushort_t* __restrict__ Bh, const ushort_t* __restrict__ Bl,
              const float* __restrict__ bias, float* __restrict__ out)
{
    __shared__ ushort_t AsH[128 * 32], AsL[128 * 32], BsH[64 * 32], BsL[64 * 32];
    const int tid  = threadIdx.x;
    const int lane = tid & 63;
    const int w    = tid >> 6;
    const int l15  = lane & 15;
    const int g    = lane >> 4;
    const int wr   = w >> 1;          // 0..1 -> 64 rows
    const int wc   = w & 1;           // 0..1 -> 32 cols
    const int n0 = blockIdx.x * 64;
    const int m0 = blockIdx.y * 128;

    const int sr  = lane >> 2;
    const int scz = (lane & 3) ^ ((sr >> 1) & 3);
    const int sc  = scz * 8;
    const int ja0 = 2 * w, ja1 = 2 * w + 1;

    const ushort_t* gAh0 = Ah + (size_t)(m0 + ja0 * 16 + sr) * 1024 + sc;
    const ushort_t* gAh1 = Ah + (size_t)(m0 + ja1 * 16 + sr) * 1024 + sc;
    const ushort_t* gAl0 = Al + (size_t)(m0 + ja0 * 16 + sr) * 1024 + sc;
    const ushort_t* gAl1 = Al + (size_t)(m0 + ja1 * 16 + sr) * 1024 + sc;
    const ushort_t* gBh0 = Bh + (size_t)(n0 + w * 16 + sr) * 1024 + sc;
    const ushort_t* gBl0 = Bl + (size_t)(n0 + w * 16 + sr) * 1024 + sc;

    const int sx  = (l15 >> 1) & 3;
    const int rd1 = (((g >> 1) + 0) ^ sx) * 8 + (g & 1) * 4;
    const int rd2 = (((g >> 1) + 2) ^ sx) * 8 + (g & 1) * 4;

    f32x4 acc[4][2];
#pragma unroll
    for (int i = 0; i < 4; ++i)
#pragma unroll
        for (int j = 0; j < 2; ++j) { acc[i][j][0] = 0.f; acc[i][j][1] = 0.f; acc[i][j][2] = 0.f; acc[i][j][3] = 0.f; }

    for (int kt = 0; kt < 32; ++kt) {
        const int k0 = kt * 32;
        if (kt) __syncthreads();
        gload16(gAh0 + k0, AsH + ja0 * 512);
        gload16(gAh1 + k0, AsH + ja1 * 512);
        gload16(gAl0 + k0, AsL + ja0 * 512);
        gload16(gAl1 + k0, AsL + ja1 * 512);
        gload16(gBh0 + k0, BsH + w * 512);
        gload16(gBl0 + k0, BsL + w * 512);
        asm volatile("s_waitcnt vmcnt(0)" ::: "memory");
        __syncthreads();

        short8 bh[2], bl[2];
#pragma unroll
        for (int nb = 0; nb < 2; ++nb) {
            const int rb = (wc * 32 + nb * 16 + l15) * 32;
            union { us4 h[2]; short8 s; } u;
            u.h[0] = *reinterpret_cast<const us4*>(BsH + rb + rd1);
            u.h[1] = *reinterpret_cast<const us4*>(BsH + rb + rd2);
            bh[nb] = u.s;
            union { us4 h[2]; short8 s; } v;
            v.h[0] = *reinterpret_cast<const us4*>(BsL + rb + rd1);
            v.h[1] = *reinterpret_cast<const us4*>(BsL + rb + rd2);
            bl[nb] = v.s;
        }
#pragma unroll
        for (int mb = 0; mb < 4; ++mb) {
            const int rb = (wr * 64 + mb * 16 + l15) * 32;
            union { us4 h[2]; short8 s; } ua;
            ua.h[0] = *reinterpret_cast<const us4*>(AsH + rb + rd1);
            ua.h[1] = *reinterpret_cast<const us4*>(AsH + rb + rd2);
            union { us4 h[2]; short8 s; } ul;
            ul.h[0] = *reinterpret_cast<const us4*>(AsL + rb + rd1);
            ul.h[1] = *reinterpret_cast<const us4*>(AsL + rb + rd2);
            const short8 ah = ua.s, al = ul.s;
#pragma unroll
            for (int nb = 0; nb < 2; ++nb) {
                acc[mb][nb] = MFMA16(ah, bh[nb], acc[mb][nb], 0, 0, 0);
                acc[mb][nb] = MFMA16(al, bh[nb], acc[mb][nb], 0, 0, 0);
                acc[mb][nb] = MFMA16(ah, bl[nb], acc[mb][nb], 0, 0, 0);
            }
        }
    }

    float bvv[2];
#pragma unroll
    for (int nb = 0; nb < 2; ++nb) bvv[nb] = bias[n0 + wc * 32 + nb * 16 + l15];
#pragma unroll
    for (int mb = 0; mb < 4; ++mb)
#pragma unroll
        for (int r = 0; r < 4; ++r) {
            const size_t row = m0 + wr * 64 + mb * 16 + 4 * g + r;
#pragma unroll
            for (int nb = 0; nb < 2; ++nb)
                out[row * 1024 + n0 + wc * 32 + nb * 16 + l15] = acc[mb][nb][r] + bvv[nb];
        }
}

// ---------------- MFMA bf16 flash attention, KVBLK=256, 8 waves / 256 q-rows ----------------
// Round-20 verified best: lacc row-sum on the MFMA pipe (B = all-1.0 bf16 is
// layout-independent so any k-permutation of pa sums exactly); lacc shares o's
// C-layout so the epilogue needs no shfl. 2 barriers/tile; staging group
// (tid>>8) stages halves {2g, 2g+1} with the verbatim 256-thread mapping;
// one softmax update per 256 KV rows; head-colocating bijective 1D grid.
__global__ __launch_bounds__(512, 2)
void attn_mfma(const ushort_t* __restrict__ Q, const ushort_t* __restrict__ K,
               const ushort_t* __restrict__ V, ushort_t* __restrict__ XHh,
               ushort_t* __restrict__ XHl)
{
    __shared__ __align__(16) ushort_t Kf[4][4096];   // [hf] 32 KB
    __shared__ __align__(16) ushort_t Vf[4][4096];   // 32 KB

    const int tid  = threadIdx.x;
    const int w    = tid >> 6;        // 0..7
    const int lane = tid & 63;
    const int l15  = lane & 15;
    const int g    = lane >> 4;

    // 1D grid 256: 8 same-head q-blocks share L%8 -> same XCD L2 (bijective)
    const int L  = blockIdx.x;
    const int qb = (L >> 3) & 7;
    const int bh = (L & 7) | ((L >> 6) << 3);
    const int b  = bh >> 4;
    const int hh = bh & 15;
    const size_t hoff = (size_t)b * S_ * E_ + (size_t)hh * S_ * D_;
    const ushort_t* Qh = Q + hoff;
    const ushort_t* Kh = K + hoff;
    const ushort_t* Vh = V + hoff;

    const int qw = qb * 256 + w * 32;   // this wave's 32 q-rows

    short8 qf[2][2];
#pragma unroll
    for (int qg = 0; qg < 2; ++qg)
#pragma unroll
        for (int m = 0; m < 2; ++m) {
            const ushort_t* src = &Qh[(size_t)(qw + 16 * qg + l15) * D_ + 32 * m + 4 * g];
            us4 lo = *reinterpret_cast<const us4*>(src);
            us4 hi = *reinterpret_cast<const us4*>(src + 16);
            union { us4 h[2]; short8 s; } u;
            u.h[0] = lo; u.h[1] = hi;
            qf[qg][m] = u.s;
        }

    // all-ones bf16 B-fragment for the l row-sum MFMA
    short8 onesf;
#pragma unroll
    for (int j = 0; j < 8; ++j) onesf[j] = (short)0x3F80;

    // staging: group (tid>>8) stages halves {2g, 2g+1}; verbatim 256-thread mapping
    const int hfS0 = (tid >> 8) * 2;
    const int ltid = tid & 255;
    const int kr  = ltid >> 2;
    const int kc0 = ltid & 3;
    const int kkc = ltid >> 4;
    const int vdc = ltid & 15;
    const int vmc = kkc >> 3;
    const int vh  = (kkc >> 2) & 1;
    const int vg  = kkc & 3;
    const int vn  = vdc >> 2;

    f32x4 o[2][4];
    f32x4 lacc[2];
#pragma unroll
    for (int qg = 0; qg < 2; ++qg) {
#pragma unroll
        for (int n = 0; n < 4; ++n)
#pragma unroll
            for (int r = 0; r < 4; ++r) o[qg][n][r] = 0.f;
#pragma unroll
        for (int r = 0; r < 4; ++r) lacc[qg][r] = 0.f;
    }

    float mrun[2] = {-1e30f, -1e30f};

    for (int kt = 0; kt < S_ / 256; ++kt) {
        // ---- global loads for this group's two halves (before barrier) ----
        us8 kreg[2][2];
        us4 vreg[2][4];
#pragma unroll
        for (int lh = 0; lh < 2; ++lh) {
            const int rowb = kt * 256 + (hfS0 + lh) * 64;
#pragma unroll
            for (int u = 0; u < 2; ++u)
                kreg[lh][u] = *reinterpret_cast<const us8*>(&Kh[(size_t)(rowb + kr) * D_ + 8 * (kc0 + 4 * u)]);
#pragma unroll
            for (int i = 0; i < 4; ++i)
                vreg[lh][i] = *reinterpret_cast<const us4*>(&Vh[(size_t)(rowb + 4 * kkc + i) * D_ + 4 * vdc]);
        }

        __syncthreads();   // previous tile's readers done

        // ---- LDS writes (verbatim verified mapping, own two halves) ----
#pragma unroll
        for (int lh = 0; lh < 2; ++lh) {
            const int hf = hfS0 + lh;
#pragma unroll
            for (int u = 0; u < 2; ++u) {
                const int c8 = kc0 + 4 * u;
                const int m = c8 >> 2;
                const int h = (c8 >> 1) & 1;
#pragma unroll
                for (int jh = 0; jh < 2; ++jh) {
                    const int gk = (2 * c8 + jh) & 3;
                    const int slot = gk * 16 + (kr & 15);
                    us4 val;
#pragma unroll
                    for (int i = 0; i < 4; ++i) val[i] = (ushort_t)kreg[lh][u][4 * jh + i];
                    *reinterpret_cast<us4*>(&Kf[hf][((((kr >> 4) * 2 + m) * 64 + slot) * 8) + h * 4]) = val;
                }
            }
#pragma unroll
            for (int jj = 0; jj < 4; ++jj) {
                us4 val;
#pragma unroll
                for (int i = 0; i < 4; ++i) val[i] = vreg[lh][i][jj];
                const int pos  = 4 * (vdc & 3) + jj;
                const int posx = pos ^ vg ^ (vn << 2);
                const int slot = vg * 16 + posx;
                *reinterpret_cast<us4*>(&Vf[hf][(((vn * 2 + vmc) * 64 + slot) * 8) + vh * 4]) = val;
            }
        }
        __syncthreads();

        // ---- QK^T for all four halves: s[qg][hf*4+kkb] ----
        f32x4 s[2][16];
#pragma unroll
        for (int hf = 0; hf < 4; ++hf) {
            short8 kf[4][2];
#pragma unroll
            for (int kkb = 0; kkb < 4; ++kkb)
#pragma unroll
                for (int m = 0; m < 2; ++m)
                    kf[kkb][m] = *reinterpret_cast<const short8*>(&Kf[hf][((kkb * 2 + m) * 64 + lane) * 8]);
#pragma unroll
            for (int qg = 0; qg < 2; ++qg)
#pragma unroll
                for (int kkb = 0; kkb < 4; ++kkb) {
                    f32x4 z; z[0] = 0.f; z[1] = 0.f; z[2] = 0.f; z[3] = 0.f;
                    z = MFMA16(kf[kkb][0], qf[qg][0], z, 0, 0, 0);
                    s[qg][hf * 4 + kkb] = MFMA16(kf[kkb][1], qf[qg][1], z, 0, 0, 0);
                }
        }

        // ---- online-softmax update per 256 KV rows (l handled by MFMA below) ----
#pragma unroll
        for (int qg = 0; qg < 2; ++qg) {
            float t = s[qg][0][0];
#pragma unroll
            for (int j = 0; j < 16; ++j)
#pragma unroll
                for (int r = 0; r < 4; ++r) t = fmaxf(t, s[qg][j][r]);
            t = fmaxf(t, __shfl_xor(t, 16));
            t = fmaxf(t, __shfl_xor(t, 32));
            const float mnew = fmaxf(mrun[qg], t);
            const float corr = __builtin_amdgcn_exp2f(mrun[qg] - mnew);

#pragma unroll
            for (int j = 0; j < 16; ++j)
#pragma unroll
                for (int r = 0; r < 4; ++r)
                    s[qg][j][r] = __builtin_amdgcn_exp2f(s[qg][j][r] - mnew);
            mrun[qg] = mnew;

#pragma unroll
            for (int r = 0; r < 4; ++r) {
                const float c4 = __shfl(corr, 4 * g + r);
                lacc[qg][r] *= c4;
#pragma unroll
                for (int n = 0; n < 4; ++n) o[qg][n][r] *= c4;
            }
        }

        // ---- PV per half (pa from s[qg][hf*4+..], vf from Vf[hf]); l via MFMA ----
#pragma unroll
        for (int hf = 0; hf < 4; ++hf) {
            short8 vf[4][2];
#pragma unroll
            for (int n = 0; n < 4; ++n)
#pragma unroll
                for (int m = 0; m < 2; ++m) {
                    const int posr = (lane & 15) ^ (lane >> 4) ^ (n << 2);
                    const int slot = (lane & 48) | posr;
                    vf[n][m] = *reinterpret_cast<const short8*>(&Vf[hf][((n * 2 + m) * 64 + slot) * 8]);
                }
#pragma unroll
            for (int qg = 0; qg < 2; ++qg) {
                short8 pa[2];
#pragma unroll
                for (int m = 0; m < 2; ++m) {
                    us8 tmp;
#pragma unroll
                    for (int r = 0; r < 4; ++r) {
                        tmp[r]     = f2bf_fast(s[qg][hf * 4 + 2 * m][r]);
                        tmp[r + 4] = f2bf_fast(s[qg][hf * 4 + 2 * m + 1][r]);
                    }
                    union { us8 u8; short8 s8; } cvt; cvt.u8 = tmp;
                    pa[m] = cvt.s8;
                }
#pragma unroll
                for (int n = 0; n < 4; ++n) {
                    o[qg][n] = MFMA16(pa[0], vf[n][0], o[qg][n], 0, 0, 0);
                    o[qg][n] = MFMA16(pa[1], vf[n][1], o[qg][n], 0, 0, 0);
                }
                lacc[qg] = MFMA16(pa[0], onesf, lacc[qg], 0, 0, 0);
                lacc[qg] = MFMA16(pa[1], onesf, lacc[qg], 0, 0, 0);
            }
        }
    }

#pragma unroll
    for (int qg = 0; qg < 2; ++qg) {
#pragma unroll
        for (int r = 0; r < 4; ++r) {
            const float iv = 1.f / lacc[qg][r];   // same C-layout as o: no shfl
            const int row = qw + 16 * qg + 4 * g + r;
            const size_t base = ((size_t)b * S_ + row) * E_ + hh * D_ + l15;
#pragma unroll
            for (int n = 0; n < 4; ++n) {
                const float vv = o[qg][n][r] * iv;
                const ushort_t hi = f2bf(vv);
                XHh[base + 16 * n] = hi;
                XHl[base + 16 * n] = f2bf(vv - bf2f(hi));
            }
        }
    }
}

extern "C" void kernel_launch(void* const* d_in, const int* in_sizes, int n_in,
                              void* d_out, int out_size, void* d_ws, size_t ws_size,
                              hipStream_t stream) {
    (void)in_sizes; (void)n_in; (void)out_size; (void)ws_size;
    const float* x  = (const float*)d_in[0];
    const float* Wq = (const float*)d_in[1];
    const float* bq = (const float*)d_in[2];
    const float* Wk = (const float*)d_in[3];
    const float* bk = (const float*)d_in[4];
    const float* Wv = (const float*)d_in[5];
    const float* bv = (const float*)d_in[6];
    const float* Wo = (const float*)d_in[7];
    const float* bo = (const float*)d_in[8];
    float* out = (float*)d_out;

    char* ws = (char*)d_ws;
    const size_t MB8 = 8ull * 1024 * 1024;
    ushort_t* xhi = (ushort_t*)(ws);             // 8 MB, reused as XHh after QKV
    ushort_t* XHl = (ushort_t*)(ws + MB8);       // 8 MB
    ushort_t* Wth = (ushort_t*)(ws + 2 * MB8);   // 8 MB  [4][1024][1024]
    ushort_t* Wtl = (ushort_t*)(ws + 3 * MB8);   // 8 MB
    ushort_t* Qb  = (ushort_t*)(ws + 4 * MB8);   // 8 MB
    ushort_t* Kb  = (ushort_t*)(ws + 5 * MB8);   // 8 MB
    ushort_t* Vb  = (ushort_t*)(ws + 6 * MB8);   // 8 MB  (total 56 MB)
    ushort_t* XHh = xhi;

    const float qalpha = 0.125f * 1.4426950408889634f;  // 1/sqrt(D) * log2(e)

    prep<<<dim3(3072), dim3(256), 0, stream>>>(x, xhi, Wq, Wk, Wv, Wo, Wth, Wtl);

    gemm_qkv<<<dim3(24, 32), dim3(256), 0, stream>>>(xhi, Wth,
                                                     bq, bk, bv, Qb, Kb, Vb, qalpha);

    attn_mfma<<<dim3(256), dim3(512), 0, stream>>>(Qb, Kb, Vb, XHh, XHl);

    gemm_o64<<<dim3(16, 32), dim3(256), 0, stream>>>(XHh, XHl,
                                                     Wth + 3ull * 1024 * 1024,
                                                     Wtl + 3ull * 1024 * 1024,
                                                     bo, out);
}